// Round 15
// baseline (390.755 us; speedup 1.0000x reference)
//
#include <hip/hip_runtime.h>

typedef unsigned long long u64;
typedef unsigned int u32;
typedef unsigned short u16;

#define N_PTS 32768
#define M_PTS 8192
#define C_IN 6
#define H_DIM 64

#define G 6
#define NCELL 216
#define NCELL_T 864
#define CW (1.0f/3.0f)

#define NBLK 256
#define NBLKD 1792
#define QG 4
#define GPC 4                  // 16-query windows per cell
#define NTASK (NCELL_T*GPC)
#define KTGT 48.0f

#define TL0 0.0494f
#define TL1 0.0740f
#define TL2 0.1110f
#define TL3 0.1736f
#define TL4 0.2600f
#define TL5 0.4000f

#define KEYMASK 0xFFFFE000u
#define IDXMASK 0x1FFFu

// ws layout (bytes):
// 0      : stats1[128]f      (zeroed)
// 512    : stats2[128]f      (zeroed)
// 1024   : gcount[864]u32    (zeroed)  -> 4480
// 4480   : accum[5]double    (zeroed)  -> 4520
// 4520   : donecnt u32, 4524: taskctr u32 (zeroed; memset 0..4544)
// 4544   : cellstart[865]u32 -> 8004 pad 8008
// 8008   : cellptr[864]u32   -> 11464 pad 11472
// 11472  : S[32768]f         -> 142544
// 142544 : P4s[32768]float4 (x,y,z,idxbits) -> 666832
// 666832 : pcell[32768]u16   -> 732368

__device__ __forceinline__ float gelu_exact(float x) {
    return 0.5f * x * (1.0f + erff(x * 0.70710678118654752f));
}
__device__ __forceinline__ float sigmoidf_(float x) {
    return 1.0f / (1.0f + expf(-x));
}

__device__ __forceinline__ u32 bitonic_sort64_u32(u32 key, int lane) {
    #pragma unroll
    for (int k = 2; k <= 64; k <<= 1) {
        #pragma unroll
        for (int j = k >> 1; j; j >>= 1) {
            u32 pk = (u32)__shfl_xor((int)key, j, 64);
            bool up = ((lane & k) == 0);
            bool tmin = (((lane & j) == 0) == up);
            key = tmin ? min(key, pk) : max(key, pk);
        }
    }
    return key;
}

// cell geometry helper (uniform across block)
__device__ __forceinline__ void cell_geom(int cid, int lo[3], int hi[3],
        float lof[3], float hif[3], bool lw[3], bool hw[3]) {
    int cx = cid % G, cy = (cid / G) % G, cz = cid / (G*G);
    int ccrd[3] = {cx, cy, cz};
    bool wall[3]; int Wn = 0;
    #pragma unroll
    for (int d = 0; d < 3; ++d) { wall[d] = (ccrd[d] == 0 || ccrd[d] == G-1); Wn += wall[d]; }
    #pragma unroll
    for (int d = 0; d < 3; ++d) {
        if (Wn >= 2 && !wall[d]) { lo[d] = min(max(ccrd[d]-2, 0), G-5); hi[d] = lo[d]+4; }
        else                     { lo[d] = min(max(ccrd[d]-1, 0), G-3); hi[d] = lo[d]+2; }
    }
    #pragma unroll
    for (int d = 0; d < 3; ++d) {
        lof[d] = -1.0f + lo[d]*CW; hif[d] = -1.0f + (hi[d]+1)*CW;
        lw[d] = (lo[d] == 0); hw[d] = (hi[d] == G-1);
    }
}

// ================= kA: cellpack + layer1 stats =================
__global__ __launch_bounds__(256) void kA(const float* __restrict__ feat,
        const float* __restrict__ coords, const float* __restrict__ W1,
        const float* __restrict__ b1, u32* __restrict__ gcount,
        u16* __restrict__ pcell, float* __restrict__ stats1) {
    __shared__ float red[512];
    int t = threadIdx.x, bid = blockIdx.x;
    if (bid < 128) {
        int n = bid * 256 + t;
        float x = coords[n*3], y = coords[n*3+1], z = coords[n*3+2];
        int cx = min(G-1, max(0, (int)floorf((x + 1.0f) * 3.0f)));
        int cy = min(G-1, max(0, (int)floorf((y + 1.0f) * 3.0f)));
        int cz = min(G-1, max(0, (int)floorf((z + 1.0f) * 3.0f)));
        int gcid = (n >> 13) * NCELL + (cz*G + cy)*G + cx;
        pcell[n] = (u16)gcid;
        atomicAdd(&gcount[gcid], 1u);
    }
    int c = t & 63, w = t >> 6;
    float w1c[C_IN];
    #pragma unroll
    for (int k = 0; k < C_IN; ++k) w1c[k] = W1[k*H_DIM + c];
    float bias = b1[c];
    float s1 = 0.f, s2 = 0.f;
    #pragma unroll 1
    for (int n = bid*8 + w*2; n < N_PTS; n += NBLK*8) {
        const float2* fa = (const float2*)(feat + n*C_IN);
        const float2* fb = (const float2*)(feat + (n+1)*C_IN);
        float2 a0 = fa[0], a1 = fa[1], a2 = fa[2];
        float2 b0 = fb[0], b1v = fb[1], b2v = fb[2];
        float ha = bias, hb = bias;
        ha = fmaf(a0.x, w1c[0], ha); ha = fmaf(a0.y, w1c[1], ha);
        ha = fmaf(a1.x, w1c[2], ha); ha = fmaf(a1.y, w1c[3], ha);
        ha = fmaf(a2.x, w1c[4], ha); ha = fmaf(a2.y, w1c[5], ha);
        hb = fmaf(b0.x, w1c[0], hb); hb = fmaf(b0.y, w1c[1], hb);
        hb = fmaf(b1v.x, w1c[2], hb); hb = fmaf(b1v.y, w1c[3], hb);
        hb = fmaf(b2v.x, w1c[4], hb); hb = fmaf(b2v.y, w1c[5], hb);
        s1 += ha + hb;
        s2 = fmaf(ha, ha, s2); s2 = fmaf(hb, hb, s2);
    }
    red[w*64 + c] = s1;
    red[256 + w*64 + c] = s2;
    __syncthreads();
    if (t < 64) {
        float a = red[t] + red[64+t] + red[128+t] + red[192+t];
        float b = red[256+t] + red[320+t] + red[384+t] + red[448+t];
        atomicAdd(&stats1[t], a);
        atomicAdd(&stats1[64+t], b);
    }
}

// ================= kB: scan (block 0) + layer2 stats (ILP-4) =================
__global__ __launch_bounds__(256) void kB(const float* __restrict__ feat,
        const float* __restrict__ W1, const float* __restrict__ b1,
        const float* __restrict__ stats1, const float* __restrict__ g1,
        const float* __restrict__ be1, const float* __restrict__ W2,
        const float* __restrict__ b2, const u32* __restrict__ gcount,
        u32* __restrict__ cellstart, u32* __restrict__ cellptr,
        float* __restrict__ stats2) {
    __shared__ float red[512];
    __shared__ u32 sc[256];
    int t = threadIdx.x, bid = blockIdx.x;
    if (bid == 0) {
        u32 loc[4]; u32 s = 0;
        #pragma unroll
        for (int j = 0; j < 4; ++j) {
            int idx = t*4 + j;
            loc[j] = (idx < NCELL_T) ? gcount[idx] : 0u;
            s += loc[j];
        }
        sc[t] = s;
        __syncthreads();
        for (int off = 1; off < 256; off <<= 1) {
            u32 v = sc[t];
            if (t >= off) v += sc[t-off];
            __syncthreads();
            sc[t] = v;
            __syncthreads();
        }
        u32 run = sc[t] - s;
        #pragma unroll
        for (int j = 0; j < 4; ++j) {
            int idx = t*4 + j;
            if (idx < NCELL_T) { cellstart[idx] = run; cellptr[idx] = run; }
            run += loc[j];
        }
        if (t == 255) cellstart[NCELL_T] = sc[255];
        __syncthreads();
    }
    int c = t & 63, w = t >> 6;
    float w2c[H_DIM];
    #pragma unroll
    for (int k = 0; k < H_DIM; ++k) w2c[k] = W2[k*H_DIM + c];
    float w1c[C_IN];
    #pragma unroll
    for (int k = 0; k < C_IN; ++k) w1c[k] = W1[k*H_DIM + c];
    float mean1 = stats1[c] * (1.0f/N_PTS);
    float var1  = stats1[64+c] * (1.0f/N_PTS) - mean1*mean1;
    float sc1 = g1[c] * rsqrtf(var1 + 1e-5f);
    float sh1 = be1[c] - mean1*sc1;
    float bias1 = b1[c], bias2 = b2[c];
    float s1 = 0.f, s2 = 0.f;
    #pragma unroll 1
    for (int n = bid*16 + w*4; n < N_PTS; n += NBLK*16) {
        float h[4], a[4], h2[4];
        #pragma unroll
        for (int p = 0; p < 4; ++p) {
            const float2* f2 = (const float2*)(feat + (n+p)*C_IN);
            float2 x0 = f2[0], x1 = f2[1], x2 = f2[2];
            h[p] = bias1;
            h[p] = fmaf(x0.x, w1c[0], h[p]); h[p] = fmaf(x0.y, w1c[1], h[p]);
            h[p] = fmaf(x1.x, w1c[2], h[p]); h[p] = fmaf(x1.y, w1c[3], h[p]);
            h[p] = fmaf(x2.x, w1c[4], h[p]); h[p] = fmaf(x2.y, w1c[5], h[p]);
            a[p] = gelu_exact(fmaf(sc1, h[p], sh1));
            h2[p] = bias2;
        }
        #pragma unroll
        for (int k = 0; k < H_DIM; ++k) {
            #pragma unroll
            for (int p = 0; p < 4; ++p)
                h2[p] = fmaf(__shfl(a[p], k, 64), w2c[k], h2[p]);
        }
        #pragma unroll
        for (int p = 0; p < 4; ++p) {
            s1 += h2[p];
            s2 = fmaf(h2[p], h2[p], s2);
        }
    }
    red[w*64 + c] = s1;
    red[256 + w*64 + c] = s2;
    __syncthreads();
    if (t < 64) {
        float a = red[t] + red[64+t] + red[128+t] + red[192+t];
        float b = red[256+t] + red[320+t] + red[384+t] + red[448+t];
        atomicAdd(&stats2[t], a);
        atomicAdd(&stats2[64+t], b);
    }
}

// ================= kC: scatter + score (ILP-4) =================
__global__ __launch_bounds__(256) void kC(const float* __restrict__ feat,
        const float* __restrict__ coords,
        const float* __restrict__ W1, const float* __restrict__ b1,
        const float* __restrict__ stats1, const float* __restrict__ g1,
        const float* __restrict__ be1, const float* __restrict__ W2,
        const float* __restrict__ b2, const float* __restrict__ stats2,
        const float* __restrict__ g2v, const float* __restrict__ be2,
        const float* __restrict__ W3, const float* __restrict__ b3,
        const u16* __restrict__ pcell, u32* __restrict__ cellptr,
        float4* __restrict__ P4s, float* __restrict__ S) {
    int t = threadIdx.x, bid = blockIdx.x;
    if (bid < 128) {
        int n = bid * 256 + t;
        float x = coords[n*3], y = coords[n*3+1], z = coords[n*3+2];
        u32 pos = atomicAdd(&cellptr[pcell[n]], 1u);
        P4s[pos] = make_float4(x, y, z, __uint_as_float((u32)(n & (M_PTS-1))));
    }
    int c = t & 63, w = t >> 6;
    float w2c[H_DIM];
    #pragma unroll
    for (int k = 0; k < H_DIM; ++k) w2c[k] = W2[k*H_DIM + c];
    float w1c[C_IN];
    #pragma unroll
    for (int k = 0; k < C_IN; ++k) w1c[k] = W1[k*H_DIM + c];
    float mean1 = stats1[c] * (1.0f/N_PTS);
    float var1  = stats1[64+c] * (1.0f/N_PTS) - mean1*mean1;
    float sc1 = g1[c] * rsqrtf(var1 + 1e-5f);
    float sh1 = be1[c] - mean1*sc1;
    float mean2 = stats2[c] * (1.0f/N_PTS);
    float var2  = stats2[64+c] * (1.0f/N_PTS) - mean2*mean2;
    float sc2 = g2v[c] * rsqrtf(var2 + 1e-5f);
    float sh2 = be2[c] - mean2*sc2;
    float bias1 = b1[c], bias2 = b2[c], w3 = W3[c], bb = b3[0];
    #pragma unroll 1
    for (int n = bid*16 + w*4; n < N_PTS; n += NBLK*16) {
        float h[4], a[4], h2[4];
        #pragma unroll
        for (int p = 0; p < 4; ++p) {
            const float2* f2 = (const float2*)(feat + (n+p)*C_IN);
            float2 x0 = f2[0], x1 = f2[1], x2 = f2[2];
            h[p] = bias1;
            h[p] = fmaf(x0.x, w1c[0], h[p]); h[p] = fmaf(x0.y, w1c[1], h[p]);
            h[p] = fmaf(x1.x, w1c[2], h[p]); h[p] = fmaf(x1.y, w1c[3], h[p]);
            h[p] = fmaf(x2.x, w1c[4], h[p]); h[p] = fmaf(x2.y, w1c[5], h[p]);
            a[p] = gelu_exact(fmaf(sc1, h[p], sh1));
            h2[p] = bias2;
        }
        #pragma unroll
        for (int k = 0; k < H_DIM; ++k) {
            #pragma unroll
            for (int p = 0; p < 4; ++p)
                h2[p] = fmaf(__shfl(a[p], k, 64), w2c[k], h2[p]);
        }
        float v[4];
        #pragma unroll
        for (int p = 0; p < 4; ++p)
            v[p] = gelu_exact(fmaf(sc2, h2[p], sh2)) * w3;
        #pragma unroll
        for (int m = 32; m; m >>= 1) {
            #pragma unroll
            for (int p = 0; p < 4; ++p) v[p] += __shfl_xor(v[p], m, 64);
        }
        if (c == 0) {
            #pragma unroll
            for (int p = 0; p < 4; ++p) S[n+p] = sigmoidf_(v[p] + bb);
        }
    }
}

// ====== kD: block dynamic queue; task = (cell, 16-query window) ======
__global__ __launch_bounds__(256) void kD(const float4* __restrict__ P4s,
        const u32* __restrict__ cellstart, const float* __restrict__ S,
        double* __restrict__ accum, u32* __restrict__ donecnt,
        u32* __restrict__ taskctr, float* __restrict__ out) {
    __shared__ u32 wavebuf[4][QG][128];   // 8 KB
    __shared__ int runsb[16], runse[16];
    __shared__ int nruns_s;
    __shared__ int curtask_s, nexttask_s;
    __shared__ u32 flistB[64];
    __shared__ u32 flnB;
    __shared__ int frunsb[16], frunse[16];
    __shared__ u32 cnt6[6];
    __shared__ u32 ovcnt;
    __shared__ float smacc;
    __shared__ double lred[4][5];

    int t = threadIdx.x;
    int lane = t & 63, w = t >> 6;
    u64 lmask = (1ull << lane) - 1ull;
    if (t == 0) { flnB = 0; curtask_s = (int)atomicAdd(taskctr, 1u); }
    __syncthreads();

    double anum=0.0, aden=0.0, aslp=0.0, asln=0.0, asmo=0.0;

    for (;;) {
        int tid = curtask_s;
        if (tid >= NTASK) break;
        if (t == 0) nexttask_s = (int)atomicAdd(taskctr, 1u);

        int cell = tid >> 2, g = tid & 3;
        int scene = cell / NCELL;
        int cid = cell - scene*NCELL;
        int sbase = scene * M_PTS;

        int gcid = scene*NCELL + cid;
        int qstart = (int)cellstart[gcid];
        int qn = (int)cellstart[gcid+1] - qstart;
        int qlo = g * 16;
        if (qlo >= qn) {   // empty window: advance
            __syncthreads();
            if (t == 0) curtask_s = nexttask_s;
            __syncthreads();
            continue;
        }
        int qhiEnd = (g == GPC-1) ? qn : min(qlo + 16, qn);

        int lo[3], hi[3]; float lof[3], hif[3]; bool lw[3], hw[3];
        cell_geom(cid, lo, hi, lof, hif, lw, hw);
        if (t == 0) {
            int nr = 0;
            int nx = hi[0]-lo[0]+1;
            for (int z = lo[2]; z <= hi[2]; ++z)
                for (int y = lo[1]; y <= hi[1]; ++y) {
                    int bc = scene*NCELL + (z*G + y)*G + lo[0];
                    runsb[nr] = (int)cellstart[bc];
                    runse[nr] = (int)cellstart[bc + nx];
                    ++nr;
                }
            nruns_s = nr;
        }
        __syncthreads();
        int nruns = nruns_s;

        for (int g0 = qstart + qlo + w*QG; g0 < qstart + qhiEnd; g0 += 16) {
            int jcount = min(QG, qstart + qhiEnd - g0);
            int qb = g0;
            float qx[QG], qy[QG], qz[QG], qs[QG], tp[QG];
            u32 qid[QG], baseq[QG];
            #pragma unroll
            for (int j = 0; j < QG; ++j) {
                int qg = qb + min(j, jcount-1);
                float4 qc = P4s[qg];
                qx[j]=qc.x; qy[j]=qc.y; qz[j]=qc.z;
                qid[j] = __float_as_uint(qc.w);
                float qsq = fmaf(qc.x, qc.x, fmaf(qc.y, qc.y, qc.z*qc.z));
                qs[j] = qsq;
                float cov = 1e9f;
                float qdv[3] = {qc.x, qc.y, qc.z};
                #pragma unroll
                for (int d = 0; d < 3; ++d) {
                    if (!lw[d]) cov = fminf(cov, qdv[d] - lof[d]);
                    if (!hw[d]) cov = fminf(cov, hif[d] - qdv[d]);
                }
                float g2 = cov*cov;
                float axx = fminf(qc.x+1.f, 1.f-qc.x);
                float ayy = fminf(qc.y+1.f, 1.f-qc.y);
                float azz = fminf(qc.z+1.f, 1.f-qc.z);
                float r = 0.224f;
                #pragma unroll
                for (int it = 0; it < 3; ++it) {
                    float ir = 1.0f / r;
                    float ux = fminf(axx*ir, 1.f), uy = fminf(ayy*ir, 1.f), uz = fminf(azz*ir, 1.f);
                    float fx = 0.25f*(2.f + 3.f*ux - ux*ux*ux);
                    float fy = 0.25f*(2.f + 3.f*uy - uy*uy*uy);
                    float fz = 0.25f*(2.f + 3.f*uz - uz*uz*uz);
                    r = cbrtf(KTGT / (4289.32f * fx * fy * fz));
                }
                tp[j] = (j < jcount) ? (fminf(r*r, g2) - qsq) : -1e30f;
                baseq[j] = 0;
            }

            for (int rr = 0; rr < nruns; ++rr) {
                int ve = runse[rr];
                for (int v0 = runsb[rr]; v0 < ve; v0 += 128) {
                    int vA = v0 + lane, vB = v0 + 64 + lane;
                    bool okA = vA < ve, okB = vB < ve;
                    float4 pA = make_float4(1e3f,1e3f,1e3f,0.f);
                    float4 pB = make_float4(1e3f,1e3f,1e3f,0.f);
                    if (okA) pA = P4s[vA];
                    if (okB) pB = P4s[vB];
                    float sqA = fmaf(pA.x, pA.x, fmaf(pA.y, pA.y, pA.z*pA.z));
                    float sqB = fmaf(pB.x, pB.x, fmaf(pB.y, pB.y, pB.z*pB.z));
                    #pragma unroll
                    for (int j = 0; j < QG; ++j) {
                        float dotA = fmaf(qx[j], pA.x, fmaf(qy[j], pA.y, qz[j]*pA.z));
                        float e2A = fmaf(-2.0f, dotA, sqA);
                        bool prA = okA && (e2A < tp[j]);
                        u64 mkA = __ballot(prA);
                        if (prA) {
                            float d2 = fmaxf(e2A + qs[j], 0.0f);
                            u32 key = (__float_as_uint(d2) & KEYMASK) | __float_as_uint(pA.w);
                            u32 pos = baseq[j] + (u32)__popcll(mkA & lmask);
                            if (pos < 128u) wavebuf[w][j][pos] = key;
                        }
                        baseq[j] += (u32)__popcll(mkA);
                        float dotB = fmaf(qx[j], pB.x, fmaf(qy[j], pB.y, qz[j]*pB.z));
                        float e2B = fmaf(-2.0f, dotB, sqB);
                        bool prB = okB && (e2B < tp[j]);
                        u64 mkB = __ballot(prB);
                        if (prB) {
                            float d2 = fmaxf(e2B + qs[j], 0.0f);
                            u32 key = (__float_as_uint(d2) & KEYMASK) | __float_as_uint(pB.w);
                            u32 pos = baseq[j] + (u32)__popcll(mkB & lmask);
                            if (pos < 128u) wavebuf[w][j][pos] = key;
                        }
                        baseq[j] += (u32)__popcll(mkB);
                    }
                }
            }

            #pragma unroll 1
            for (int j = 0; j < QG; ++j) {
                if (j >= jcount) continue;
                int qg = qb + j;
                u32 M = baseq[j];
                if (M < 32u || M > 128u) {
                    if (lane == 0) {
                        u32 idx = atomicAdd(&flnB, 1u);
                        if (idx < 64u) flistB[idx] = ((u32)cell << 16) | (u32)qg;
                    }
                    continue;
                }
                u32 k0 = (lane < (int)min(M, 64u)) ? wavebuf[w][j][lane] : 0xFFFFFFFFu;
                k0 = bitonic_sort64_u32(k0, lane);
                if (M > 64u) {
                    u32 k1 = (lane < (int)(M - 64u)) ? wavebuf[w][j][64 + lane] : 0xFFFFFFFFu;
                    k1 = bitonic_sort64_u32(k1, lane);
                    u32 pk = (u32)__shfl((int)k1, 63 - lane, 64);
                    u32 lo2 = min(k0, pk);
                    #pragma unroll
                    for (int jj = 32; jj; jj >>= 1) {
                        u32 pj = (u32)__shfl_xor((int)lo2, jj, 64);
                        lo2 = ((lane & jj) == 0) ? min(lo2, pj) : max(lo2, pj);
                    }
                    k0 = lo2;
                }
                float si = S[sbase + (int)qid[j]];
                float smsum = 0.f;
                if (lane < 32) {
                    float d2 = __uint_as_float(k0 & KEYMASK);
                    u32 jo = k0 & IDXMASK;
                    float sj = S[sbase + (int)jo];
                    float sd = fabsf(si - sj);
                    float sim = 1.0f - sd;
                    if (lane < 16) {
                        float d = sqrtf(fmaxf(d2, 1e-24f));
                        float wgt = expf(-10.0f*d);
                        anum += (double)(wgt*sd*sd);
                        aden += (double)wgt;
                        aslp += (double)logf(sigmoidf_(2.0f*sim) + 1e-8f);
                        if (lane < 8) smsum += sj;
                    } else {
                        asln += (double)logf(sigmoidf_(-2.0f*sim) + 1e-8f);
                    }
                }
                #pragma unroll
                for (int m = 32; m; m >>= 1) smsum += __shfl_xor(smsum, m, 64);
                if (lane == 0) {
                    float dd = si - smsum*0.125f;
                    asmo += (double)(dd*dd);
                }
            }
        }
        __syncthreads();
        if (t == 0) curtask_s = nexttask_s;
        __syncthreads();
    }
    __syncthreads();

    // ---- rare block-cooperative ladder fallback (per-entry cell geometry) ----
    int nf = min((int)flnB, 64);
    u32* ovbuf = &wavebuf[0][0][0];    // 2048 u32
    for (int f = 0; f < nf; ++f) {
        u32 ent = flistB[f];
        int fqg = (int)(ent & 0xFFFFu);
        int fcell = (int)(ent >> 16);
        int scene = fcell / NCELL;
        int cid = fcell - scene*NCELL;
        int sbase = scene * M_PTS;
        int lo[3], hi[3]; float lof[3], hif[3]; bool lw[3], hw[3];
        cell_geom(cid, lo, hi, lof, hif, lw, hw);
        int nx = hi[0]-lo[0]+1, ny = hi[1]-lo[1]+1, nz = hi[2]-lo[2]+1;
        int nruns = ny*nz;
        if (t < nruns) {
            int yy = t % ny, zz = t / ny;
            int bc = scene*NCELL + ((lo[2]+zz)*G + (lo[1]+yy))*G + lo[0];
            frunsb[t] = (int)cellstart[bc];
            frunse[t] = (int)cellstart[bc + nx];
        }
        float4 fqc = P4s[fqg];
        float fsq = fmaf(fqc.x, fqc.x, fmaf(fqc.y, fqc.y, fqc.z*fqc.z));
        float fcov = 1e9f;
        float fqd[3] = {fqc.x, fqc.y, fqc.z};
        #pragma unroll
        for (int d = 0; d < 3; ++d) {
            if (!lw[d]) fcov = fminf(fcov, fqd[d] - lof[d]);
            if (!hw[d]) fcov = fminf(fcov, hif[d] - fqd[d]);
        }
        float fg2 = fcov*fcov;
        if (t < 6) cnt6[t] = 0;
        if (t == 0) { ovcnt = 0; smacc = 0.f; }
        __syncthreads();
        u32 c0=0,c1=0,c2=0,c3=0,c4=0,c5=0;
        for (int rr = 0; rr < nruns; ++rr) {
            for (int v = frunsb[rr] + t; v < frunse[rr]; v += 256) {
                float4 pp = P4s[v];
                float sq = fmaf(pp.x, pp.x, fmaf(pp.y, pp.y, pp.z*pp.z));
                float dot = fmaf(fqc.x, pp.x, fmaf(fqc.y, pp.y, fqc.z*pp.z));
                float e2 = fmaf(-2.0f, dot, sq);
                c0 += (e2 < TL0-fsq); c1 += (e2 < TL1-fsq); c2 += (e2 < TL2-fsq);
                c3 += (e2 < TL3-fsq); c4 += (e2 < TL4-fsq); c5 += (e2 < TL5-fsq);
            }
        }
        #pragma unroll
        for (int m = 32; m; m >>= 1) {
            c0 += __shfl_xor(c0, m, 64); c1 += __shfl_xor(c1, m, 64);
            c2 += __shfl_xor(c2, m, 64); c3 += __shfl_xor(c3, m, 64);
            c4 += __shfl_xor(c4, m, 64); c5 += __shfl_xor(c5, m, 64);
        }
        if ((t & 63) == 0) {
            atomicAdd(&cnt6[0], c0); atomicAdd(&cnt6[1], c1);
            atomicAdd(&cnt6[2], c2); atomicAdd(&cnt6[3], c3);
            atomicAdd(&cnt6[4], c4); atomicAdd(&cnt6[5], c5);
        }
        __syncthreads();
        float tau = TL2;
        if (TL3 <= fg2) tau = TL3;
        if (TL4 <= fg2) tau = TL4;
        if (TL5 <= fg2) tau = TL5;
        if      (cnt6[0] >= 32u) tau = TL0;
        else if (cnt6[1] >= 32u) tau = TL1;
        else if (cnt6[2] >= 32u) tau = TL2;
        else if (TL3 <= fg2 && cnt6[3] >= 32u) tau = TL3;
        else if (TL4 <= fg2 && cnt6[4] >= 32u) tau = TL4;
        else if (TL5 <= fg2 && cnt6[5] >= 32u) tau = TL5;
        float ftp = tau - fsq;
        for (int rr = 0; rr < nruns; ++rr) {
            for (int v = frunsb[rr] + t; v < frunse[rr]; v += 256) {
                float4 pp = P4s[v];
                float sq = fmaf(pp.x, pp.x, fmaf(pp.y, pp.y, pp.z*pp.z));
                float dot = fmaf(fqc.x, pp.x, fmaf(fqc.y, pp.y, fqc.z*pp.z));
                float e2 = fmaf(-2.0f, dot, sq);
                if (e2 < ftp) {
                    float d2 = fmaxf(e2 + fsq, 0.0f);
                    u32 key = (__float_as_uint(d2) & KEYMASK) | __float_as_uint(pp.w);
                    u32 pos = atomicAdd(&ovcnt, 1u);
                    if (pos < 2048u) ovbuf[pos] = key;
                }
            }
        }
        __syncthreads();
        u32 Mf = min(ovcnt, 2048u);
        float fsi = S[sbase + (int)__float_as_uint(fqc.w)];
        for (int i = t; i < (int)Mf; i += 256) {
            u32 mykey = ovbuf[i];
            u32 rank = 0;
            for (u32 jj = 0; jj < Mf; ++jj) rank += (ovbuf[jj] < mykey);
            if (rank < 32u) {
                float d2 = __uint_as_float(mykey & KEYMASK);
                u32 jo = mykey & IDXMASK;
                float sj = S[sbase + (int)jo];
                float sd = fabsf(fsi - sj);
                float sim = 1.0f - sd;
                if (rank < 16u) {
                    float d = sqrtf(fmaxf(d2, 1e-24f));
                    float wgt = expf(-10.0f*d);
                    anum += (double)(wgt*sd*sd);
                    aden += (double)wgt;
                    aslp += (double)logf(sigmoidf_(2.0f*sim) + 1e-8f);
                    if (rank < 8u) atomicAdd(&smacc, sj);
                } else {
                    asln += (double)logf(sigmoidf_(-2.0f*sim) + 1e-8f);
                }
            }
        }
        __syncthreads();
        if (t == 0) {
            float dd = fsi - smacc*0.125f;
            asmo += (double)(dd*dd);
        }
        __syncthreads();
    }

    // ---- block reduce + global accumulate + fused final ----
    double v[5] = {anum, aden, aslp, asln, asmo};
    #pragma unroll
    for (int k = 0; k < 5; ++k) {
        for (int m = 32; m; m >>= 1) v[k] += __shfl_xor(v[k], m, 64);
    }
    if (lane == 0) {
        #pragma unroll
        for (int k = 0; k < 5; ++k) lred[w][k] = v[k];
    }
    __syncthreads();
    if (t == 0) {
        #pragma unroll
        for (int k = 0; k < 5; ++k)
            atomicAdd(&accum[k], lred[0][k] + lred[1][k] + lred[2][k] + lred[3][k]);
        __threadfence();
        u32 old = atomicAdd(donecnt, 1u);
        if (old == (u32)(NBLKD - 1)) {
            double a0 = atomicAdd(&accum[0], 0.0);
            double a1 = atomicAdd(&accum[1], 0.0);
            double a2 = atomicAdd(&accum[2], 0.0);
            double a3 = atomicAdd(&accum[3], 0.0);
            double a4 = atomicAdd(&accum[4], 0.0);
            double loss_loc = a0 / fmax(a1, 1e-8);
            double inv = 1.0 / ((double)N_PTS * 16.0);
            double loss_con = -(a2 * inv) - (a3 * inv);
            double loss_sm = a4 / (double)N_PTS;
            out[0] = (float)(loss_loc + 0.5*loss_con + 0.2*loss_sm);
        }
    }
}

extern "C" void kernel_launch(void* const* d_in, const int* in_sizes, int n_in,
                              void* d_out, int out_size, void* d_ws, size_t ws_size,
                              hipStream_t stream) {
    const float* feat   = (const float*)d_in[0];
    const float* coords = (const float*)d_in[1];
    const float* W1 = (const float*)d_in[2];
    const float* b1 = (const float*)d_in[3];
    const float* g1 = (const float*)d_in[4];
    const float* be1= (const float*)d_in[5];
    const float* W2 = (const float*)d_in[6];
    const float* b2 = (const float*)d_in[7];
    const float* g2 = (const float*)d_in[8];
    const float* be2= (const float*)d_in[9];
    const float* W3 = (const float*)d_in[10];
    const float* b3 = (const float*)d_in[11];
    char* ws = (char*)d_ws;

    float* stats1   = (float*)(ws);
    float* stats2   = (float*)(ws + 512);
    u32* gcount     = (u32*)(ws + 1024);
    double* accum   = (double*)(ws + 4480);
    u32* donecnt    = (u32*)(ws + 4520);
    u32* taskctr    = (u32*)(ws + 4524);
    u32* cellstart  = (u32*)(ws + 4544);
    u32* cellptr    = (u32*)(ws + 8008);
    float* S        = (float*)(ws + 11472);
    float4* P4s     = (float4*)(ws + 142544);
    u16* pcell      = (u16*)(ws + 666832);

    hipMemsetAsync(d_ws, 0, 4544, stream);

    hipLaunchKernelGGL(kA, dim3(NBLK), dim3(256), 0, stream,
                       feat, coords, W1, b1, gcount, pcell, stats1);
    hipLaunchKernelGGL(kB, dim3(NBLK), dim3(256), 0, stream,
                       feat, W1, b1, stats1, g1, be1, W2, b2,
                       gcount, cellstart, cellptr, stats2);
    hipLaunchKernelGGL(kC, dim3(NBLK), dim3(256), 0, stream,
                       feat, coords, W1, b1, stats1, g1, be1, W2, b2,
                       stats2, g2, be2, W3, b3, pcell, cellptr, P4s, S);
    hipLaunchKernelGGL(kD, dim3(NBLKD), dim3(256), 0, stream,
                       P4s, cellstart, S, accum, donecnt, taskctr, (float*)d_out);
}

// Round 16
// 315.683 us; speedup vs baseline: 1.2378x; 1.2378x over previous
//
#include <hip/hip_runtime.h>

typedef unsigned long long u64;
typedef unsigned int u32;
typedef unsigned short u16;

#define N_PTS 32768
#define M_PTS 8192
#define C_IN 6
#define H_DIM 64

#define G 6
#define NCELL 216
#define NCELL_T 864
#define CW (1.0f/3.0f)

#define NBLK 256
#define NBLKD 1024
#define QG 4
#define NTASK (NCELL_T*2)      // (cell, half) tasks
#define KTGT 48.0f
#define MAXCH 48

#define TL0 0.0494f
#define TL1 0.0740f
#define TL2 0.1110f
#define TL3 0.1736f
#define TL4 0.2600f
#define TL5 0.4000f

#define KEYMASK 0xFFFFE000u
#define IDXMASK 0x1FFFu

// ws layout (bytes):
// 0      : stats1[128]f      (zeroed)
// 512    : stats2[128]f      (zeroed)
// 1024   : gcount[864]u32    (zeroed)  -> 4480
// 4480   : accum[5]double    (zeroed)  -> 4520
// 4520   : donecnt u32, 4524: taskctr u32 (zeroed; memset 0..4544)
// 4544   : cellstart[865]u32 -> 8004 pad 8008
// 8008   : cellptr[864]u32   -> 11464 pad 11472
// 11472  : S[32768]f         -> 142544
// 142544 : P4s[32768]float4 (x,y,z,idxbits) -> 666832
// 666832 : pcell[32768]u16   -> 732368

__device__ __forceinline__ float gelu_exact(float x) {
    return 0.5f * x * (1.0f + erff(x * 0.70710678118654752f));
}
__device__ __forceinline__ float sigmoidf_(float x) {
    return 1.0f / (1.0f + expf(-x));
}

__device__ __forceinline__ u32 bitonic_sort64_u32(u32 key, int lane) {
    #pragma unroll
    for (int k = 2; k <= 64; k <<= 1) {
        #pragma unroll
        for (int j = k >> 1; j; j >>= 1) {
            u32 pk = (u32)__shfl_xor((int)key, j, 64);
            bool up = ((lane & k) == 0);
            bool tmin = (((lane & j) == 0) == up);
            key = tmin ? min(key, pk) : max(key, pk);
        }
    }
    return key;
}

__device__ __forceinline__ void cell_geom(int cid, int lo[3], int hi[3],
        float lof[3], float hif[3], bool lw[3], bool hw[3]) {
    int cx = cid % G, cy = (cid / G) % G, cz = cid / (G*G);
    int ccrd[3] = {cx, cy, cz};
    bool wall[3]; int Wn = 0;
    #pragma unroll
    for (int d = 0; d < 3; ++d) { wall[d] = (ccrd[d] == 0 || ccrd[d] == G-1); Wn += wall[d]; }
    #pragma unroll
    for (int d = 0; d < 3; ++d) {
        if (Wn >= 2 && !wall[d]) { lo[d] = min(max(ccrd[d]-2, 0), G-5); hi[d] = lo[d]+4; }
        else                     { lo[d] = min(max(ccrd[d]-1, 0), G-3); hi[d] = lo[d]+2; }
    }
    #pragma unroll
    for (int d = 0; d < 3; ++d) {
        lof[d] = -1.0f + lo[d]*CW; hif[d] = -1.0f + (hi[d]+1)*CW;
        lw[d] = (lo[d] == 0); hw[d] = (hi[d] == G-1);
    }
}

// ================= kA: cellpack + layer1 stats =================
__global__ __launch_bounds__(256) void kA(const float* __restrict__ feat,
        const float* __restrict__ coords, const float* __restrict__ W1,
        const float* __restrict__ b1, u32* __restrict__ gcount,
        u16* __restrict__ pcell, float* __restrict__ stats1) {
    __shared__ float red[512];
    int t = threadIdx.x, bid = blockIdx.x;
    if (bid < 128) {
        int n = bid * 256 + t;
        float x = coords[n*3], y = coords[n*3+1], z = coords[n*3+2];
        int cx = min(G-1, max(0, (int)floorf((x + 1.0f) * 3.0f)));
        int cy = min(G-1, max(0, (int)floorf((y + 1.0f) * 3.0f)));
        int cz = min(G-1, max(0, (int)floorf((z + 1.0f) * 3.0f)));
        int gcid = (n >> 13) * NCELL + (cz*G + cy)*G + cx;
        pcell[n] = (u16)gcid;
        atomicAdd(&gcount[gcid], 1u);
    }
    int c = t & 63, w = t >> 6;
    float w1c[C_IN];
    #pragma unroll
    for (int k = 0; k < C_IN; ++k) w1c[k] = W1[k*H_DIM + c];
    float bias = b1[c];
    float s1 = 0.f, s2 = 0.f;
    #pragma unroll 1
    for (int n = bid*8 + w*2; n < N_PTS; n += NBLK*8) {
        const float2* fa = (const float2*)(feat + n*C_IN);
        const float2* fb = (const float2*)(feat + (n+1)*C_IN);
        float2 a0 = fa[0], a1 = fa[1], a2 = fa[2];
        float2 b0 = fb[0], b1v = fb[1], b2v = fb[2];
        float ha = bias, hb = bias;
        ha = fmaf(a0.x, w1c[0], ha); ha = fmaf(a0.y, w1c[1], ha);
        ha = fmaf(a1.x, w1c[2], ha); ha = fmaf(a1.y, w1c[3], ha);
        ha = fmaf(a2.x, w1c[4], ha); ha = fmaf(a2.y, w1c[5], ha);
        hb = fmaf(b0.x, w1c[0], hb); hb = fmaf(b0.y, w1c[1], hb);
        hb = fmaf(b1v.x, w1c[2], hb); hb = fmaf(b1v.y, w1c[3], hb);
        hb = fmaf(b2v.x, w1c[4], hb); hb = fmaf(b2v.y, w1c[5], hb);
        s1 += ha + hb;
        s2 = fmaf(ha, ha, s2); s2 = fmaf(hb, hb, s2);
    }
    red[w*64 + c] = s1;
    red[256 + w*64 + c] = s2;
    __syncthreads();
    if (t < 64) {
        float a = red[t] + red[64+t] + red[128+t] + red[192+t];
        float b = red[256+t] + red[320+t] + red[384+t] + red[448+t];
        atomicAdd(&stats1[t], a);
        atomicAdd(&stats1[64+t], b);
    }
}

// ================= kB: scan (block 0) + layer2 stats (ILP-4) =================
__global__ __launch_bounds__(256) void kB(const float* __restrict__ feat,
        const float* __restrict__ W1, const float* __restrict__ b1,
        const float* __restrict__ stats1, const float* __restrict__ g1,
        const float* __restrict__ be1, const float* __restrict__ W2,
        const float* __restrict__ b2, const u32* __restrict__ gcount,
        u32* __restrict__ cellstart, u32* __restrict__ cellptr,
        float* __restrict__ stats2) {
    __shared__ float red[512];
    __shared__ u32 sc[256];
    int t = threadIdx.x, bid = blockIdx.x;
    if (bid == 0) {
        u32 loc[4]; u32 s = 0;
        #pragma unroll
        for (int j = 0; j < 4; ++j) {
            int idx = t*4 + j;
            loc[j] = (idx < NCELL_T) ? gcount[idx] : 0u;
            s += loc[j];
        }
        sc[t] = s;
        __syncthreads();
        for (int off = 1; off < 256; off <<= 1) {
            u32 v = sc[t];
            if (t >= off) v += sc[t-off];
            __syncthreads();
            sc[t] = v;
            __syncthreads();
        }
        u32 run = sc[t] - s;
        #pragma unroll
        for (int j = 0; j < 4; ++j) {
            int idx = t*4 + j;
            if (idx < NCELL_T) { cellstart[idx] = run; cellptr[idx] = run; }
            run += loc[j];
        }
        if (t == 255) cellstart[NCELL_T] = sc[255];
        __syncthreads();
    }
    int c = t & 63, w = t >> 6;
    float w2c[H_DIM];
    #pragma unroll
    for (int k = 0; k < H_DIM; ++k) w2c[k] = W2[k*H_DIM + c];
    float w1c[C_IN];
    #pragma unroll
    for (int k = 0; k < C_IN; ++k) w1c[k] = W1[k*H_DIM + c];
    float mean1 = stats1[c] * (1.0f/N_PTS);
    float var1  = stats1[64+c] * (1.0f/N_PTS) - mean1*mean1;
    float sc1 = g1[c] * rsqrtf(var1 + 1e-5f);
    float sh1 = be1[c] - mean1*sc1;
    float bias1 = b1[c], bias2 = b2[c];
    float s1 = 0.f, s2 = 0.f;
    #pragma unroll 1
    for (int n = bid*16 + w*4; n < N_PTS; n += NBLK*16) {
        float h[4], a[4], h2[4];
        #pragma unroll
        for (int p = 0; p < 4; ++p) {
            const float2* f2 = (const float2*)(feat + (n+p)*C_IN);
            float2 x0 = f2[0], x1 = f2[1], x2 = f2[2];
            h[p] = bias1;
            h[p] = fmaf(x0.x, w1c[0], h[p]); h[p] = fmaf(x0.y, w1c[1], h[p]);
            h[p] = fmaf(x1.x, w1c[2], h[p]); h[p] = fmaf(x1.y, w1c[3], h[p]);
            h[p] = fmaf(x2.x, w1c[4], h[p]); h[p] = fmaf(x2.y, w1c[5], h[p]);
            a[p] = gelu_exact(fmaf(sc1, h[p], sh1));
            h2[p] = bias2;
        }
        #pragma unroll
        for (int k = 0; k < H_DIM; ++k) {
            #pragma unroll
            for (int p = 0; p < 4; ++p)
                h2[p] = fmaf(__shfl(a[p], k, 64), w2c[k], h2[p]);
        }
        #pragma unroll
        for (int p = 0; p < 4; ++p) {
            s1 += h2[p];
            s2 = fmaf(h2[p], h2[p], s2);
        }
    }
    red[w*64 + c] = s1;
    red[256 + w*64 + c] = s2;
    __syncthreads();
    if (t < 64) {
        float a = red[t] + red[64+t] + red[128+t] + red[192+t];
        float b = red[256+t] + red[320+t] + red[384+t] + red[448+t];
        atomicAdd(&stats2[t], a);
        atomicAdd(&stats2[64+t], b);
    }
}

// ================= kC: scatter + score (ILP-4) =================
__global__ __launch_bounds__(256) void kC(const float* __restrict__ feat,
        const float* __restrict__ coords,
        const float* __restrict__ W1, const float* __restrict__ b1,
        const float* __restrict__ stats1, const float* __restrict__ g1,
        const float* __restrict__ be1, const float* __restrict__ W2,
        const float* __restrict__ b2, const float* __restrict__ stats2,
        const float* __restrict__ g2v, const float* __restrict__ be2,
        const float* __restrict__ W3, const float* __restrict__ b3,
        const u16* __restrict__ pcell, u32* __restrict__ cellptr,
        float4* __restrict__ P4s, float* __restrict__ S) {
    int t = threadIdx.x, bid = blockIdx.x;
    if (bid < 128) {
        int n = bid * 256 + t;
        float x = coords[n*3], y = coords[n*3+1], z = coords[n*3+2];
        u32 pos = atomicAdd(&cellptr[pcell[n]], 1u);
        P4s[pos] = make_float4(x, y, z, __uint_as_float((u32)(n & (M_PTS-1))));
    }
    int c = t & 63, w = t >> 6;
    float w2c[H_DIM];
    #pragma unroll
    for (int k = 0; k < H_DIM; ++k) w2c[k] = W2[k*H_DIM + c];
    float w1c[C_IN];
    #pragma unroll
    for (int k = 0; k < C_IN; ++k) w1c[k] = W1[k*H_DIM + c];
    float mean1 = stats1[c] * (1.0f/N_PTS);
    float var1  = stats1[64+c] * (1.0f/N_PTS) - mean1*mean1;
    float sc1 = g1[c] * rsqrtf(var1 + 1e-5f);
    float sh1 = be1[c] - mean1*sc1;
    float mean2 = stats2[c] * (1.0f/N_PTS);
    float var2  = stats2[64+c] * (1.0f/N_PTS) - mean2*mean2;
    float sc2 = g2v[c] * rsqrtf(var2 + 1e-5f);
    float sh2 = be2[c] - mean2*sc2;
    float bias1 = b1[c], bias2 = b2[c], w3 = W3[c], bb = b3[0];
    #pragma unroll 1
    for (int n = bid*16 + w*4; n < N_PTS; n += NBLK*16) {
        float h[4], a[4], h2[4];
        #pragma unroll
        for (int p = 0; p < 4; ++p) {
            const float2* f2 = (const float2*)(feat + (n+p)*C_IN);
            float2 x0 = f2[0], x1 = f2[1], x2 = f2[2];
            h[p] = bias1;
            h[p] = fmaf(x0.x, w1c[0], h[p]); h[p] = fmaf(x0.y, w1c[1], h[p]);
            h[p] = fmaf(x1.x, w1c[2], h[p]); h[p] = fmaf(x1.y, w1c[3], h[p]);
            h[p] = fmaf(x2.x, w1c[4], h[p]); h[p] = fmaf(x2.y, w1c[5], h[p]);
            a[p] = gelu_exact(fmaf(sc1, h[p], sh1));
            h2[p] = bias2;
        }
        #pragma unroll
        for (int k = 0; k < H_DIM; ++k) {
            #pragma unroll
            for (int p = 0; p < 4; ++p)
                h2[p] = fmaf(__shfl(a[p], k, 64), w2c[k], h2[p]);
        }
        float v[4];
        #pragma unroll
        for (int p = 0; p < 4; ++p)
            v[p] = gelu_exact(fmaf(sc2, h2[p], sh2)) * w3;
        #pragma unroll
        for (int m = 32; m; m >>= 1) {
            #pragma unroll
            for (int p = 0; p < 4; ++p) v[p] += __shfl_xor(v[p], m, 64);
        }
        if (c == 0) {
            #pragma unroll
            for (int p = 0; p < 4; ++p) S[n+p] = sigmoidf_(v[p] + bb);
        }
    }
}

// ====== kD: block dynamic queue, (cell,half) tasks, pipelined chunk scan =====
__global__ __launch_bounds__(256) void kD(const float4* __restrict__ P4s,
        const u32* __restrict__ cellstart, const float* __restrict__ S,
        double* __restrict__ accum, u32* __restrict__ donecnt,
        u32* __restrict__ taskctr, float* __restrict__ out) {
    __shared__ u32 wavebuf[4][QG][128];   // 8 KB
    __shared__ int chb[MAXCH];            // chunk bases
    __shared__ int chn[MAXCH];            // chunk counts (<=128)
    __shared__ int nch_s;
    __shared__ int curtask_s, nexttask_s;
    __shared__ u32 flistB[64];
    __shared__ u32 flnB;
    __shared__ int frunsb[16], frunse[16];
    __shared__ u32 cnt6[6];
    __shared__ u32 ovcnt;
    __shared__ float smacc;
    __shared__ double lred[4][5];

    int t = threadIdx.x;
    int lane = t & 63, w = t >> 6;
    u64 lmask = (1ull << lane) - 1ull;
    if (t == 0) { flnB = 0; curtask_s = (int)atomicAdd(taskctr, 1u); }
    __syncthreads();

    double anum=0.0, aden=0.0, aslp=0.0, asln=0.0, asmo=0.0;

    for (;;) {
        int tid = curtask_s;
        if (tid >= NTASK) break;
        if (t == 0) nexttask_s = (int)atomicAdd(taskctr, 1u);

        int cell = tid >> 1, part = tid & 1;
        int scene = cell / NCELL;
        int cid = cell - scene*NCELL;
        int sbase = scene * M_PTS;

        int lo[3], hi[3]; float lof[3], hif[3]; bool lw[3], hw[3];
        cell_geom(cid, lo, hi, lof, hif, lw, hw);
        if (t == 0) {
            int nc = 0;
            int nx = hi[0]-lo[0]+1;
            for (int z = lo[2]; z <= hi[2]; ++z)
                for (int y = lo[1]; y <= hi[1]; ++y) {
                    int bc = scene*NCELL + (z*G + y)*G + lo[0];
                    int b = (int)cellstart[bc], e = (int)cellstart[bc + nx];
                    for (; b < e && nc < MAXCH; b += 128) {
                        chb[nc] = b;
                        chn[nc] = min(128, e - b);
                        ++nc;
                    }
                }
            nch_s = nc;
        }
        int gcid = scene*NCELL + cid;
        int qstart = (int)cellstart[gcid];
        int qn = (int)cellstart[gcid+1] - qstart;
        __syncthreads();
        int nchunk = nch_s;
        int hq = (qn + 1) >> 1;
        int hqs = qstart + part * hq;
        int hqn = qn - part * hq; if (hqn > hq) hqn = hq; if (hqn < 0) hqn = 0;

        for (int g0 = w*QG; g0 < hqn; g0 += 4*QG) {
            int jcount = min(QG, hqn - g0);
            int qb = hqs + g0;
            float qx[QG], qy[QG], qz[QG], qs[QG], tp[QG];
            u32 qid[QG], baseq[QG];
            #pragma unroll
            for (int j = 0; j < QG; ++j) {
                int qg = qb + min(j, jcount-1);
                float4 qc = P4s[qg];
                qx[j]=qc.x; qy[j]=qc.y; qz[j]=qc.z;
                qid[j] = __float_as_uint(qc.w);
                float qsq = fmaf(qc.x, qc.x, fmaf(qc.y, qc.y, qc.z*qc.z));
                qs[j] = qsq;
                float cov = 1e9f;
                float qdv[3] = {qc.x, qc.y, qc.z};
                #pragma unroll
                for (int d = 0; d < 3; ++d) {
                    if (!lw[d]) cov = fminf(cov, qdv[d] - lof[d]);
                    if (!hw[d]) cov = fminf(cov, hif[d] - qdv[d]);
                }
                float g2 = cov*cov;
                float axx = fminf(qc.x+1.f, 1.f-qc.x);
                float ayy = fminf(qc.y+1.f, 1.f-qc.y);
                float azz = fminf(qc.z+1.f, 1.f-qc.z);
                float r = 0.224f;
                #pragma unroll
                for (int it = 0; it < 3; ++it) {
                    float ir = 1.0f / r;
                    float ux = fminf(axx*ir, 1.f), uy = fminf(ayy*ir, 1.f), uz = fminf(azz*ir, 1.f);
                    float fx = 0.25f*(2.f + 3.f*ux - ux*ux*ux);
                    float fy = 0.25f*(2.f + 3.f*uy - uy*uy*uy);
                    float fz = 0.25f*(2.f + 3.f*uz - uz*uz*uz);
                    r = cbrtf(KTGT / (4289.32f * fx * fy * fz));
                }
                tp[j] = (j < jcount) ? (fminf(r*r, g2) - qsq) : -1e30f;
                baseq[j] = 0;
            }

            // ---- pipelined chunk scan: prefetch chunk c+1 while processing c
            float4 pA = make_float4(1e3f,1e3f,1e3f,0.f);
            float4 pB = make_float4(1e3f,1e3f,1e3f,0.f);
            bool okA = false, okB = false;
            {
                int b0 = chb[0], n0 = chn[0];
                okA = lane < n0; okB = lane + 64 < n0;
                if (okA) pA = P4s[b0 + lane];
                if (okB) pB = P4s[b0 + 64 + lane];
            }
            for (int c = 0; c < nchunk; ++c) {
                float4 nA = make_float4(1e3f,1e3f,1e3f,0.f);
                float4 nB = make_float4(1e3f,1e3f,1e3f,0.f);
                bool noA = false, noB = false;
                if (c + 1 < nchunk) {
                    int b1 = chb[c+1], n1 = chn[c+1];
                    noA = lane < n1; noB = lane + 64 < n1;
                    if (noA) nA = P4s[b1 + lane];
                    if (noB) nB = P4s[b1 + 64 + lane];
                }
                float sqA = fmaf(pA.x, pA.x, fmaf(pA.y, pA.y, pA.z*pA.z));
                float sqB = fmaf(pB.x, pB.x, fmaf(pB.y, pB.y, pB.z*pB.z));
                #pragma unroll
                for (int j = 0; j < QG; ++j) {
                    float dotA = fmaf(qx[j], pA.x, fmaf(qy[j], pA.y, qz[j]*pA.z));
                    float e2A = fmaf(-2.0f, dotA, sqA);
                    bool prA = okA && (e2A < tp[j]);
                    u64 mkA = __ballot(prA);
                    if (prA) {
                        float d2 = fmaxf(e2A + qs[j], 0.0f);
                        u32 key = (__float_as_uint(d2) & KEYMASK) | __float_as_uint(pA.w);
                        u32 pos = baseq[j] + (u32)__popcll(mkA & lmask);
                        if (pos < 128u) wavebuf[w][j][pos] = key;
                    }
                    baseq[j] += (u32)__popcll(mkA);
                    float dotB = fmaf(qx[j], pB.x, fmaf(qy[j], pB.y, qz[j]*pB.z));
                    float e2B = fmaf(-2.0f, dotB, sqB);
                    bool prB = okB && (e2B < tp[j]);
                    u64 mkB = __ballot(prB);
                    if (prB) {
                        float d2 = fmaxf(e2B + qs[j], 0.0f);
                        u32 key = (__float_as_uint(d2) & KEYMASK) | __float_as_uint(pB.w);
                        u32 pos = baseq[j] + (u32)__popcll(mkB & lmask);
                        if (pos < 128u) wavebuf[w][j][pos] = key;
                    }
                    baseq[j] += (u32)__popcll(mkB);
                }
                pA = nA; pB = nB; okA = noA; okB = noB;
            }

            // per-query sort + eval
            #pragma unroll 1
            for (int j = 0; j < QG; ++j) {
                if (j >= jcount) continue;
                int qg = qb + j;
                u32 M = baseq[j];
                if (M < 32u || M > 128u) {
                    if (lane == 0) {
                        u32 idx = atomicAdd(&flnB, 1u);
                        if (idx < 64u) flistB[idx] = ((u32)cell << 16) | (u32)qg;
                    }
                    continue;
                }
                u32 k0 = (lane < (int)min(M, 64u)) ? wavebuf[w][j][lane] : 0xFFFFFFFFu;
                k0 = bitonic_sort64_u32(k0, lane);
                if (M > 64u) {
                    u32 k1 = (lane < (int)(M - 64u)) ? wavebuf[w][j][64 + lane] : 0xFFFFFFFFu;
                    k1 = bitonic_sort64_u32(k1, lane);
                    u32 pk = (u32)__shfl((int)k1, 63 - lane, 64);
                    u32 lo2 = min(k0, pk);
                    #pragma unroll
                    for (int jj = 32; jj; jj >>= 1) {
                        u32 pj = (u32)__shfl_xor((int)lo2, jj, 64);
                        lo2 = ((lane & jj) == 0) ? min(lo2, pj) : max(lo2, pj);
                    }
                    k0 = lo2;
                }
                float si = S[sbase + (int)qid[j]];
                float smsum = 0.f;
                if (lane < 32) {
                    float d2 = __uint_as_float(k0 & KEYMASK);
                    u32 jo = k0 & IDXMASK;
                    float sj = S[sbase + (int)jo];
                    float sd = fabsf(si - sj);
                    float sim = 1.0f - sd;
                    if (lane < 16) {
                        float d = sqrtf(fmaxf(d2, 1e-24f));
                        float wgt = expf(-10.0f*d);
                        anum += (double)(wgt*sd*sd);
                        aden += (double)wgt;
                        aslp += (double)logf(sigmoidf_(2.0f*sim) + 1e-8f);
                        if (lane < 8) smsum += sj;
                    } else {
                        asln += (double)logf(sigmoidf_(-2.0f*sim) + 1e-8f);
                    }
                }
                #pragma unroll
                for (int m = 32; m; m >>= 1) smsum += __shfl_xor(smsum, m, 64);
                if (lane == 0) {
                    float dd = si - smsum*0.125f;
                    asmo += (double)(dd*dd);
                }
            }
        }
        __syncthreads();
        if (t == 0) curtask_s = nexttask_s;
        __syncthreads();
    }
    __syncthreads();

    // ---- rare block-cooperative ladder fallback (per-entry cell geometry) ----
    int nf = min((int)flnB, 64);
    u32* ovbuf = &wavebuf[0][0][0];    // 2048 u32
    for (int f = 0; f < nf; ++f) {
        u32 ent = flistB[f];
        int fqg = (int)(ent & 0xFFFFu);
        int fcell = (int)(ent >> 16);
        int scene = fcell / NCELL;
        int cid = fcell - scene*NCELL;
        int sbase = scene * M_PTS;
        int lo[3], hi[3]; float lof[3], hif[3]; bool lw[3], hw[3];
        cell_geom(cid, lo, hi, lof, hif, lw, hw);
        int nx = hi[0]-lo[0]+1, ny = hi[1]-lo[1]+1, nz = hi[2]-lo[2]+1;
        int nruns = ny*nz;
        if (t < nruns) {
            int yy = t % ny, zz = t / ny;
            int bc = scene*NCELL + ((lo[2]+zz)*G + (lo[1]+yy))*G + lo[0];
            frunsb[t] = (int)cellstart[bc];
            frunse[t] = (int)cellstart[bc + nx];
        }
        float4 fqc = P4s[fqg];
        float fsq = fmaf(fqc.x, fqc.x, fmaf(fqc.y, fqc.y, fqc.z*fqc.z));
        float fcov = 1e9f;
        float fqd[3] = {fqc.x, fqc.y, fqc.z};
        #pragma unroll
        for (int d = 0; d < 3; ++d) {
            if (!lw[d]) fcov = fminf(fcov, fqd[d] - lof[d]);
            if (!hw[d]) fcov = fminf(fcov, hif[d] - fqd[d]);
        }
        float fg2 = fcov*fcov;
        if (t < 6) cnt6[t] = 0;
        if (t == 0) { ovcnt = 0; smacc = 0.f; }
        __syncthreads();
        u32 c0=0,c1=0,c2=0,c3=0,c4=0,c5=0;
        for (int rr = 0; rr < nruns; ++rr) {
            for (int v = frunsb[rr] + t; v < frunse[rr]; v += 256) {
                float4 pp = P4s[v];
                float sq = fmaf(pp.x, pp.x, fmaf(pp.y, pp.y, pp.z*pp.z));
                float dot = fmaf(fqc.x, pp.x, fmaf(fqc.y, pp.y, fqc.z*pp.z));
                float e2 = fmaf(-2.0f, dot, sq);
                c0 += (e2 < TL0-fsq); c1 += (e2 < TL1-fsq); c2 += (e2 < TL2-fsq);
                c3 += (e2 < TL3-fsq); c4 += (e2 < TL4-fsq); c5 += (e2 < TL5-fsq);
            }
        }
        #pragma unroll
        for (int m = 32; m; m >>= 1) {
            c0 += __shfl_xor(c0, m, 64); c1 += __shfl_xor(c1, m, 64);
            c2 += __shfl_xor(c2, m, 64); c3 += __shfl_xor(c3, m, 64);
            c4 += __shfl_xor(c4, m, 64); c5 += __shfl_xor(c5, m, 64);
        }
        if ((t & 63) == 0) {
            atomicAdd(&cnt6[0], c0); atomicAdd(&cnt6[1], c1);
            atomicAdd(&cnt6[2], c2); atomicAdd(&cnt6[3], c3);
            atomicAdd(&cnt6[4], c4); atomicAdd(&cnt6[5], c5);
        }
        __syncthreads();
        float tau = TL2;
        if (TL3 <= fg2) tau = TL3;
        if (TL4 <= fg2) tau = TL4;
        if (TL5 <= fg2) tau = TL5;
        if      (cnt6[0] >= 32u) tau = TL0;
        else if (cnt6[1] >= 32u) tau = TL1;
        else if (cnt6[2] >= 32u) tau = TL2;
        else if (TL3 <= fg2 && cnt6[3] >= 32u) tau = TL3;
        else if (TL4 <= fg2 && cnt6[4] >= 32u) tau = TL4;
        else if (TL5 <= fg2 && cnt6[5] >= 32u) tau = TL5;
        float ftp = tau - fsq;
        for (int rr = 0; rr < nruns; ++rr) {
            for (int v = frunsb[rr] + t; v < frunse[rr]; v += 256) {
                float4 pp = P4s[v];
                float sq = fmaf(pp.x, pp.x, fmaf(pp.y, pp.y, pp.z*pp.z));
                float dot = fmaf(fqc.x, pp.x, fmaf(fqc.y, pp.y, fqc.z*pp.z));
                float e2 = fmaf(-2.0f, dot, sq);
                if (e2 < ftp) {
                    float d2 = fmaxf(e2 + fsq, 0.0f);
                    u32 key = (__float_as_uint(d2) & KEYMASK) | __float_as_uint(pp.w);
                    u32 pos = atomicAdd(&ovcnt, 1u);
                    if (pos < 2048u) ovbuf[pos] = key;
                }
            }
        }
        __syncthreads();
        u32 Mf = min(ovcnt, 2048u);
        float fsi = S[sbase + (int)__float_as_uint(fqc.w)];
        for (int i = t; i < (int)Mf; i += 256) {
            u32 mykey = ovbuf[i];
            u32 rank = 0;
            for (u32 jj = 0; jj < Mf; ++jj) rank += (ovbuf[jj] < mykey);
            if (rank < 32u) {
                float d2 = __uint_as_float(mykey & KEYMASK);
                u32 jo = mykey & IDXMASK;
                float sj = S[sbase + (int)jo];
                float sd = fabsf(fsi - sj);
                float sim = 1.0f - sd;
                if (rank < 16u) {
                    float d = sqrtf(fmaxf(d2, 1e-24f));
                    float wgt = expf(-10.0f*d);
                    anum += (double)(wgt*sd*sd);
                    aden += (double)wgt;
                    aslp += (double)logf(sigmoidf_(2.0f*sim) + 1e-8f);
                    if (rank < 8u) atomicAdd(&smacc, sj);
                } else {
                    asln += (double)logf(sigmoidf_(-2.0f*sim) + 1e-8f);
                }
            }
        }
        __syncthreads();
        if (t == 0) {
            float dd = fsi - smacc*0.125f;
            asmo += (double)(dd*dd);
        }
        __syncthreads();
    }

    // ---- block reduce + global accumulate + fused final ----
    double v[5] = {anum, aden, aslp, asln, asmo};
    #pragma unroll
    for (int k = 0; k < 5; ++k) {
        for (int m = 32; m; m >>= 1) v[k] += __shfl_xor(v[k], m, 64);
    }
    if (lane == 0) {
        #pragma unroll
        for (int k = 0; k < 5; ++k) lred[w][k] = v[k];
    }
    __syncthreads();
    if (t == 0) {
        #pragma unroll
        for (int k = 0; k < 5; ++k)
            atomicAdd(&accum[k], lred[0][k] + lred[1][k] + lred[2][k] + lred[3][k]);
        __threadfence();
        u32 old = atomicAdd(donecnt, 1u);
        if (old == (u32)(NBLKD - 1)) {
            double a0 = atomicAdd(&accum[0], 0.0);
            double a1 = atomicAdd(&accum[1], 0.0);
            double a2 = atomicAdd(&accum[2], 0.0);
            double a3 = atomicAdd(&accum[3], 0.0);
            double a4 = atomicAdd(&accum[4], 0.0);
            double loss_loc = a0 / fmax(a1, 1e-8);
            double inv = 1.0 / ((double)N_PTS * 16.0);
            double loss_con = -(a2 * inv) - (a3 * inv);
            double loss_sm = a4 / (double)N_PTS;
            out[0] = (float)(loss_loc + 0.5*loss_con + 0.2*loss_sm);
        }
    }
}

extern "C" void kernel_launch(void* const* d_in, const int* in_sizes, int n_in,
                              void* d_out, int out_size, void* d_ws, size_t ws_size,
                              hipStream_t stream) {
    const float* feat   = (const float*)d_in[0];
    const float* coords = (const float*)d_in[1];
    const float* W1 = (const float*)d_in[2];
    const float* b1 = (const float*)d_in[3];
    const float* g1 = (const float*)d_in[4];
    const float* be1= (const float*)d_in[5];
    const float* W2 = (const float*)d_in[6];
    const float* b2 = (const float*)d_in[7];
    const float* g2 = (const float*)d_in[8];
    const float* be2= (const float*)d_in[9];
    const float* W3 = (const float*)d_in[10];
    const float* b3 = (const float*)d_in[11];
    char* ws = (char*)d_ws;

    float* stats1   = (float*)(ws);
    float* stats2   = (float*)(ws + 512);
    u32* gcount     = (u32*)(ws + 1024);
    double* accum   = (double*)(ws + 4480);
    u32* donecnt    = (u32*)(ws + 4520);
    u32* taskctr    = (u32*)(ws + 4524);
    u32* cellstart  = (u32*)(ws + 4544);
    u32* cellptr    = (u32*)(ws + 8008);
    float* S        = (float*)(ws + 11472);
    float4* P4s     = (float4*)(ws + 142544);
    u16* pcell      = (u16*)(ws + 666832);

    hipMemsetAsync(d_ws, 0, 4544, stream);

    hipLaunchKernelGGL(kA, dim3(NBLK), dim3(256), 0, stream,
                       feat, coords, W1, b1, gcount, pcell, stats1);
    hipLaunchKernelGGL(kB, dim3(NBLK), dim3(256), 0, stream,
                       feat, W1, b1, stats1, g1, be1, W2, b2,
                       gcount, cellstart, cellptr, stats2);
    hipLaunchKernelGGL(kC, dim3(NBLK), dim3(256), 0, stream,
                       feat, coords, W1, b1, stats1, g1, be1, W2, b2,
                       stats2, g2, be2, W3, b3, pcell, cellptr, P4s, S);
    hipLaunchKernelGGL(kD, dim3(NBLKD), dim3(256), 0, stream,
                       P4s, cellstart, S, accum, donecnt, taskctr, (float*)d_out);
}

// Round 17
// 308.816 us; speedup vs baseline: 1.2653x; 1.0222x over previous
//
#include <hip/hip_runtime.h>

typedef unsigned long long u64;
typedef unsigned int u32;
typedef unsigned short u16;

#define N_PTS 32768
#define M_PTS 8192
#define C_IN 6
#define H_DIM 64

#define G 6
#define NCELL 216
#define NCELL_T 864
#define CW (1.0f/3.0f)

#define NBLK 256
#define NBLKD 1024
#define QG 4
#define NTASK (NCELL_T*2)      // (cell, half) tasks
#define KTGT 48.0f
#define MAXCH 48

#define TL0 0.0494f
#define TL1 0.0740f
#define TL2 0.1110f
#define TL3 0.1736f
#define TL4 0.2600f
#define TL5 0.4000f

#define KEYMASK 0xFFFFE000u
#define IDXMASK 0x1FFFu

// ws layout (bytes):
// 0      : stats1[128]f      (zeroed)
// 512    : stats2[128]f      (zeroed)
// 1024   : gcount[864]u32    (zeroed)  -> 4480
// 4480   : accum[5]double    (zeroed)  -> 4520
// 4520   : donecnt u32, 4524: taskctr u32 (zeroed; memset 0..4544)
// 4544   : cellstart[865]u32 -> 8004 pad 8008
// 8008   : cellptr[864]u32   -> 11464 pad 11472
// 11472  : S[32768]f         -> 142544
// 142544 : P4s[32768]float4 (x,y,z,idxbits) -> 666832
// 666832 : pcell[32768]u16   -> 732368

__device__ __forceinline__ float gelu_exact(float x) {
    return 0.5f * x * (1.0f + erff(x * 0.70710678118654752f));
}
__device__ __forceinline__ float sigmoidf_(float x) {
    return 1.0f / (1.0f + expf(-x));
}

__device__ __forceinline__ u32 bitonic_sort64_u32(u32 key, int lane) {
    #pragma unroll
    for (int k = 2; k <= 64; k <<= 1) {
        #pragma unroll
        for (int j = k >> 1; j; j >>= 1) {
            u32 pk = (u32)__shfl_xor((int)key, j, 64);
            bool up = ((lane & k) == 0);
            bool tmin = (((lane & j) == 0) == up);
            key = tmin ? min(key, pk) : max(key, pk);
        }
    }
    return key;
}

__device__ __forceinline__ void cell_geom(int cid, int lo[3], int hi[3],
        float lof[3], float hif[3], bool lw[3], bool hw[3]) {
    int cx = cid % G, cy = (cid / G) % G, cz = cid / (G*G);
    int ccrd[3] = {cx, cy, cz};
    bool wall[3]; int Wn = 0;
    #pragma unroll
    for (int d = 0; d < 3; ++d) { wall[d] = (ccrd[d] == 0 || ccrd[d] == G-1); Wn += wall[d]; }
    #pragma unroll
    for (int d = 0; d < 3; ++d) {
        if (Wn >= 2 && !wall[d]) { lo[d] = min(max(ccrd[d]-2, 0), G-5); hi[d] = lo[d]+4; }
        else                     { lo[d] = min(max(ccrd[d]-1, 0), G-3); hi[d] = lo[d]+2; }
    }
    #pragma unroll
    for (int d = 0; d < 3; ++d) {
        lof[d] = -1.0f + lo[d]*CW; hif[d] = -1.0f + (hi[d]+1)*CW;
        lw[d] = (lo[d] == 0); hw[d] = (hi[d] == G-1);
    }
}

// ================= kA: cellpack + layer1 stats =================
__global__ __launch_bounds__(256) void kA(const float* __restrict__ feat,
        const float* __restrict__ coords, const float* __restrict__ W1,
        const float* __restrict__ b1, u32* __restrict__ gcount,
        u16* __restrict__ pcell, float* __restrict__ stats1) {
    __shared__ float red[512];
    int t = threadIdx.x, bid = blockIdx.x;
    if (bid < 128) {
        int n = bid * 256 + t;
        float x = coords[n*3], y = coords[n*3+1], z = coords[n*3+2];
        int cx = min(G-1, max(0, (int)floorf((x + 1.0f) * 3.0f)));
        int cy = min(G-1, max(0, (int)floorf((y + 1.0f) * 3.0f)));
        int cz = min(G-1, max(0, (int)floorf((z + 1.0f) * 3.0f)));
        int gcid = (n >> 13) * NCELL + (cz*G + cy)*G + cx;
        pcell[n] = (u16)gcid;
        atomicAdd(&gcount[gcid], 1u);
    }
    int c = t & 63, w = t >> 6;
    float w1c[C_IN];
    #pragma unroll
    for (int k = 0; k < C_IN; ++k) w1c[k] = W1[k*H_DIM + c];
    float bias = b1[c];
    float s1 = 0.f, s2 = 0.f;
    #pragma unroll 1
    for (int n = bid*8 + w*2; n < N_PTS; n += NBLK*8) {
        const float2* fa = (const float2*)(feat + n*C_IN);
        const float2* fb = (const float2*)(feat + (n+1)*C_IN);
        float2 a0 = fa[0], a1 = fa[1], a2 = fa[2];
        float2 b0 = fb[0], b1v = fb[1], b2v = fb[2];
        float ha = bias, hb = bias;
        ha = fmaf(a0.x, w1c[0], ha); ha = fmaf(a0.y, w1c[1], ha);
        ha = fmaf(a1.x, w1c[2], ha); ha = fmaf(a1.y, w1c[3], ha);
        ha = fmaf(a2.x, w1c[4], ha); ha = fmaf(a2.y, w1c[5], ha);
        hb = fmaf(b0.x, w1c[0], hb); hb = fmaf(b0.y, w1c[1], hb);
        hb = fmaf(b1v.x, w1c[2], hb); hb = fmaf(b1v.y, w1c[3], hb);
        hb = fmaf(b2v.x, w1c[4], hb); hb = fmaf(b2v.y, w1c[5], hb);
        s1 += ha + hb;
        s2 = fmaf(ha, ha, s2); s2 = fmaf(hb, hb, s2);
    }
    red[w*64 + c] = s1;
    red[256 + w*64 + c] = s2;
    __syncthreads();
    if (t < 64) {
        float a = red[t] + red[64+t] + red[128+t] + red[192+t];
        float b = red[256+t] + red[320+t] + red[384+t] + red[448+t];
        atomicAdd(&stats1[t], a);
        atomicAdd(&stats1[64+t], b);
    }
}

// ================= kB: scan (block 0) + layer2 stats (ILP-4) =================
__global__ __launch_bounds__(256) void kB(const float* __restrict__ feat,
        const float* __restrict__ W1, const float* __restrict__ b1,
        const float* __restrict__ stats1, const float* __restrict__ g1,
        const float* __restrict__ be1, const float* __restrict__ W2,
        const float* __restrict__ b2, const u32* __restrict__ gcount,
        u32* __restrict__ cellstart, u32* __restrict__ cellptr,
        float* __restrict__ stats2) {
    __shared__ float red[512];
    __shared__ u32 sc[256];
    int t = threadIdx.x, bid = blockIdx.x;
    if (bid == 0) {
        u32 loc[4]; u32 s = 0;
        #pragma unroll
        for (int j = 0; j < 4; ++j) {
            int idx = t*4 + j;
            loc[j] = (idx < NCELL_T) ? gcount[idx] : 0u;
            s += loc[j];
        }
        sc[t] = s;
        __syncthreads();
        for (int off = 1; off < 256; off <<= 1) {
            u32 v = sc[t];
            if (t >= off) v += sc[t-off];
            __syncthreads();
            sc[t] = v;
            __syncthreads();
        }
        u32 run = sc[t] - s;
        #pragma unroll
        for (int j = 0; j < 4; ++j) {
            int idx = t*4 + j;
            if (idx < NCELL_T) { cellstart[idx] = run; cellptr[idx] = run; }
            run += loc[j];
        }
        if (t == 255) cellstart[NCELL_T] = sc[255];
        __syncthreads();
    }
    int c = t & 63, w = t >> 6;
    float w2c[H_DIM];
    #pragma unroll
    for (int k = 0; k < H_DIM; ++k) w2c[k] = W2[k*H_DIM + c];
    float w1c[C_IN];
    #pragma unroll
    for (int k = 0; k < C_IN; ++k) w1c[k] = W1[k*H_DIM + c];
    float mean1 = stats1[c] * (1.0f/N_PTS);
    float var1  = stats1[64+c] * (1.0f/N_PTS) - mean1*mean1;
    float sc1 = g1[c] * rsqrtf(var1 + 1e-5f);
    float sh1 = be1[c] - mean1*sc1;
    float bias1 = b1[c], bias2 = b2[c];
    float s1 = 0.f, s2 = 0.f;
    #pragma unroll 1
    for (int n = bid*16 + w*4; n < N_PTS; n += NBLK*16) {
        float h[4], a[4], h2[4];
        #pragma unroll
        for (int p = 0; p < 4; ++p) {
            const float2* f2 = (const float2*)(feat + (n+p)*C_IN);
            float2 x0 = f2[0], x1 = f2[1], x2 = f2[2];
            h[p] = bias1;
            h[p] = fmaf(x0.x, w1c[0], h[p]); h[p] = fmaf(x0.y, w1c[1], h[p]);
            h[p] = fmaf(x1.x, w1c[2], h[p]); h[p] = fmaf(x1.y, w1c[3], h[p]);
            h[p] = fmaf(x2.x, w1c[4], h[p]); h[p] = fmaf(x2.y, w1c[5], h[p]);
            a[p] = gelu_exact(fmaf(sc1, h[p], sh1));
            h2[p] = bias2;
        }
        #pragma unroll
        for (int k = 0; k < H_DIM; ++k) {
            #pragma unroll
            for (int p = 0; p < 4; ++p)
                h2[p] = fmaf(__shfl(a[p], k, 64), w2c[k], h2[p]);
        }
        #pragma unroll
        for (int p = 0; p < 4; ++p) {
            s1 += h2[p];
            s2 = fmaf(h2[p], h2[p], s2);
        }
    }
    red[w*64 + c] = s1;
    red[256 + w*64 + c] = s2;
    __syncthreads();
    if (t < 64) {
        float a = red[t] + red[64+t] + red[128+t] + red[192+t];
        float b = red[256+t] + red[320+t] + red[384+t] + red[448+t];
        atomicAdd(&stats2[t], a);
        atomicAdd(&stats2[64+t], b);
    }
}

// ================= kC: scatter + score (ILP-4) =================
__global__ __launch_bounds__(256) void kC(const float* __restrict__ feat,
        const float* __restrict__ coords,
        const float* __restrict__ W1, const float* __restrict__ b1,
        const float* __restrict__ stats1, const float* __restrict__ g1,
        const float* __restrict__ be1, const float* __restrict__ W2,
        const float* __restrict__ b2, const float* __restrict__ stats2,
        const float* __restrict__ g2v, const float* __restrict__ be2,
        const float* __restrict__ W3, const float* __restrict__ b3,
        const u16* __restrict__ pcell, u32* __restrict__ cellptr,
        float4* __restrict__ P4s, float* __restrict__ S) {
    int t = threadIdx.x, bid = blockIdx.x;
    if (bid < 128) {
        int n = bid * 256 + t;
        float x = coords[n*3], y = coords[n*3+1], z = coords[n*3+2];
        u32 pos = atomicAdd(&cellptr[pcell[n]], 1u);
        P4s[pos] = make_float4(x, y, z, __uint_as_float((u32)(n & (M_PTS-1))));
    }
    int c = t & 63, w = t >> 6;
    float w2c[H_DIM];
    #pragma unroll
    for (int k = 0; k < H_DIM; ++k) w2c[k] = W2[k*H_DIM + c];
    float w1c[C_IN];
    #pragma unroll
    for (int k = 0; k < C_IN; ++k) w1c[k] = W1[k*H_DIM + c];
    float mean1 = stats1[c] * (1.0f/N_PTS);
    float var1  = stats1[64+c] * (1.0f/N_PTS) - mean1*mean1;
    float sc1 = g1[c] * rsqrtf(var1 + 1e-5f);
    float sh1 = be1[c] - mean1*sc1;
    float mean2 = stats2[c] * (1.0f/N_PTS);
    float var2  = stats2[64+c] * (1.0f/N_PTS) - mean2*mean2;
    float sc2 = g2v[c] * rsqrtf(var2 + 1e-5f);
    float sh2 = be2[c] - mean2*sc2;
    float bias1 = b1[c], bias2 = b2[c], w3 = W3[c], bb = b3[0];
    #pragma unroll 1
    for (int n = bid*16 + w*4; n < N_PTS; n += NBLK*16) {
        float h[4], a[4], h2[4];
        #pragma unroll
        for (int p = 0; p < 4; ++p) {
            const float2* f2 = (const float2*)(feat + (n+p)*C_IN);
            float2 x0 = f2[0], x1 = f2[1], x2 = f2[2];
            h[p] = bias1;
            h[p] = fmaf(x0.x, w1c[0], h[p]); h[p] = fmaf(x0.y, w1c[1], h[p]);
            h[p] = fmaf(x1.x, w1c[2], h[p]); h[p] = fmaf(x1.y, w1c[3], h[p]);
            h[p] = fmaf(x2.x, w1c[4], h[p]); h[p] = fmaf(x2.y, w1c[5], h[p]);
            a[p] = gelu_exact(fmaf(sc1, h[p], sh1));
            h2[p] = bias2;
        }
        #pragma unroll
        for (int k = 0; k < H_DIM; ++k) {
            #pragma unroll
            for (int p = 0; p < 4; ++p)
                h2[p] = fmaf(__shfl(a[p], k, 64), w2c[k], h2[p]);
        }
        float v[4];
        #pragma unroll
        for (int p = 0; p < 4; ++p)
            v[p] = gelu_exact(fmaf(sc2, h2[p], sh2)) * w3;
        #pragma unroll
        for (int m = 32; m; m >>= 1) {
            #pragma unroll
            for (int p = 0; p < 4; ++p) v[p] += __shfl_xor(v[p], m, 64);
        }
        if (c == 0) {
            #pragma unroll
            for (int p = 0; p < 4; ++p) S[n+p] = sigmoidf_(v[p] + bb);
        }
    }
}

// ====== kD: block queue, (cell,half) tasks, LDS-atomic collection ======
__global__ __launch_bounds__(256) void kD(const float4* __restrict__ P4s,
        const u32* __restrict__ cellstart, const float* __restrict__ S,
        double* __restrict__ accum, u32* __restrict__ donecnt,
        u32* __restrict__ taskctr, float* __restrict__ out) {
    __shared__ u32 wavebuf[4][QG][128];   // 8 KB
    __shared__ u32 wcnt[4][QG];
    __shared__ int chb[MAXCH];
    __shared__ int chn[MAXCH];
    __shared__ int nch_s;
    __shared__ int curtask_s, nexttask_s;
    __shared__ u32 flistB[64];
    __shared__ u32 flnB;
    __shared__ int frunsb[16], frunse[16];
    __shared__ u32 cnt6[6];
    __shared__ u32 ovcnt;
    __shared__ float smacc;
    __shared__ double lred[4][5];

    int t = threadIdx.x;
    int lane = t & 63, w = t >> 6;
    if (t == 0) { flnB = 0; curtask_s = (int)atomicAdd(taskctr, 1u); }
    __syncthreads();

    double anum=0.0, aden=0.0, aslp=0.0, asln=0.0, asmo=0.0;

    for (;;) {
        int tid = curtask_s;
        if (tid >= NTASK) break;
        if (t == 0) nexttask_s = (int)atomicAdd(taskctr, 1u);

        int cell = tid >> 1, part = tid & 1;
        int scene = cell / NCELL;
        int cid = cell - scene*NCELL;
        int sbase = scene * M_PTS;

        int lo[3], hi[3]; float lof[3], hif[3]; bool lw[3], hw[3];
        cell_geom(cid, lo, hi, lof, hif, lw, hw);
        if (t == 0) {
            int nc = 0;
            int nx = hi[0]-lo[0]+1;
            for (int z = lo[2]; z <= hi[2]; ++z)
                for (int y = lo[1]; y <= hi[1]; ++y) {
                    int bc = scene*NCELL + (z*G + y)*G + lo[0];
                    int b = (int)cellstart[bc], e = (int)cellstart[bc + nx];
                    for (; b < e && nc < MAXCH; b += 128) {
                        chb[nc] = b;
                        chn[nc] = min(128, e - b);
                        ++nc;
                    }
                }
            nch_s = nc;
        }
        int gcid = scene*NCELL + cid;
        int qstart = (int)cellstart[gcid];
        int qn = (int)cellstart[gcid+1] - qstart;
        __syncthreads();
        int nchunk = nch_s;
        int hq = (qn + 1) >> 1;
        int hqs = qstart + part * hq;
        int hqn = qn - part * hq; if (hqn > hq) hqn = hq; if (hqn < 0) hqn = 0;

        for (int g0 = w*QG; g0 < hqn; g0 += 4*QG) {
            int jcount = min(QG, hqn - g0);
            int qb = hqs + g0;
            float qx[QG], qy[QG], qz[QG], qs[QG], tp[QG];
            u32 qid[QG];
            if (lane < QG) wcnt[w][lane] = 0;
            #pragma unroll
            for (int j = 0; j < QG; ++j) {
                int qg = qb + min(j, jcount-1);
                float4 qc = P4s[qg];
                qx[j]=qc.x; qy[j]=qc.y; qz[j]=qc.z;
                qid[j] = __float_as_uint(qc.w);
                float qsq = fmaf(qc.x, qc.x, fmaf(qc.y, qc.y, qc.z*qc.z));
                qs[j] = qsq;
                float cov = 1e9f;
                float qdv[3] = {qc.x, qc.y, qc.z};
                #pragma unroll
                for (int d = 0; d < 3; ++d) {
                    if (!lw[d]) cov = fminf(cov, qdv[d] - lof[d]);
                    if (!hw[d]) cov = fminf(cov, hif[d] - qdv[d]);
                }
                float g2 = cov*cov;
                float axx = fminf(qc.x+1.f, 1.f-qc.x);
                float ayy = fminf(qc.y+1.f, 1.f-qc.y);
                float azz = fminf(qc.z+1.f, 1.f-qc.z);
                float r = 0.224f;
                #pragma unroll
                for (int it = 0; it < 3; ++it) {
                    float ir = 1.0f / r;
                    float ux = fminf(axx*ir, 1.f), uy = fminf(ayy*ir, 1.f), uz = fminf(azz*ir, 1.f);
                    float fx = 0.25f*(2.f + 3.f*ux - ux*ux*ux);
                    float fy = 0.25f*(2.f + 3.f*uy - uy*uy*uy);
                    float fz = 0.25f*(2.f + 3.f*uz - uz*uz*uz);
                    r = cbrtf(KTGT / (4289.32f * fx * fy * fz));
                }
                tp[j] = (j < jcount) ? (fminf(r*r, g2) - qsq) : -1e30f;
            }

            // ---- pipelined chunk scan; hits collected via per-wave LDS atomics
            float4 pA = make_float4(1e3f,1e3f,1e3f,0.f);
            float4 pB = make_float4(1e3f,1e3f,1e3f,0.f);
            bool okA = false, okB = false;
            {
                int b0 = chb[0], n0 = chn[0];
                okA = lane < n0; okB = lane + 64 < n0;
                if (okA) pA = P4s[b0 + lane];
                if (okB) pB = P4s[b0 + 64 + lane];
            }
            for (int c = 0; c < nchunk; ++c) {
                float4 nA = make_float4(1e3f,1e3f,1e3f,0.f);
                float4 nB = make_float4(1e3f,1e3f,1e3f,0.f);
                bool noA = false, noB = false;
                if (c + 1 < nchunk) {
                    int b1 = chb[c+1], n1 = chn[c+1];
                    noA = lane < n1; noB = lane + 64 < n1;
                    if (noA) nA = P4s[b1 + lane];
                    if (noB) nB = P4s[b1 + 64 + lane];
                }
                float sqA = fmaf(pA.x, pA.x, fmaf(pA.y, pA.y, pA.z*pA.z));
                float sqB = fmaf(pB.x, pB.x, fmaf(pB.y, pB.y, pB.z*pB.z));
                #pragma unroll
                for (int j = 0; j < QG; ++j) {
                    float dotA = fmaf(qx[j], pA.x, fmaf(qy[j], pA.y, qz[j]*pA.z));
                    float e2A = fmaf(-2.0f, dotA, sqA);
                    if (okA && e2A < tp[j]) {
                        float d2 = fmaxf(e2A + qs[j], 0.0f);
                        u32 key = (__float_as_uint(d2) & KEYMASK) | __float_as_uint(pA.w);
                        u32 pos = atomicAdd(&wcnt[w][j], 1u);
                        if (pos < 128u) wavebuf[w][j][pos] = key;
                    }
                    float dotB = fmaf(qx[j], pB.x, fmaf(qy[j], pB.y, qz[j]*pB.z));
                    float e2B = fmaf(-2.0f, dotB, sqB);
                    if (okB && e2B < tp[j]) {
                        float d2 = fmaxf(e2B + qs[j], 0.0f);
                        u32 key = (__float_as_uint(d2) & KEYMASK) | __float_as_uint(pB.w);
                        u32 pos = atomicAdd(&wcnt[w][j], 1u);
                        if (pos < 128u) wavebuf[w][j][pos] = key;
                    }
                }
                pA = nA; pB = nB; okA = noA; okB = noB;
            }

            // per-query sort + eval
            #pragma unroll 1
            for (int j = 0; j < QG; ++j) {
                if (j >= jcount) continue;
                int qg = qb + j;
                u32 M = wcnt[w][j];
                if (M < 32u || M > 128u) {
                    if (lane == 0) {
                        u32 idx = atomicAdd(&flnB, 1u);
                        if (idx < 64u) flistB[idx] = ((u32)cell << 16) | (u32)qg;
                    }
                    continue;
                }
                u32 k0 = (lane < (int)min(M, 64u)) ? wavebuf[w][j][lane] : 0xFFFFFFFFu;
                k0 = bitonic_sort64_u32(k0, lane);
                if (M > 64u) {
                    u32 k1 = (lane < (int)(M - 64u)) ? wavebuf[w][j][64 + lane] : 0xFFFFFFFFu;
                    k1 = bitonic_sort64_u32(k1, lane);
                    u32 pk = (u32)__shfl((int)k1, 63 - lane, 64);
                    u32 lo2 = min(k0, pk);
                    #pragma unroll
                    for (int jj = 32; jj; jj >>= 1) {
                        u32 pj = (u32)__shfl_xor((int)lo2, jj, 64);
                        lo2 = ((lane & jj) == 0) ? min(lo2, pj) : max(lo2, pj);
                    }
                    k0 = lo2;
                }
                float si = S[sbase + (int)qid[j]];
                float smsum = 0.f;
                if (lane < 32) {
                    float d2 = __uint_as_float(k0 & KEYMASK);
                    u32 jo = k0 & IDXMASK;
                    float sj = S[sbase + (int)jo];
                    float sd = fabsf(si - sj);
                    float sim = 1.0f - sd;
                    if (lane < 16) {
                        float d = sqrtf(fmaxf(d2, 1e-24f));
                        float wgt = expf(-10.0f*d);
                        anum += (double)(wgt*sd*sd);
                        aden += (double)wgt;
                        aslp += (double)logf(sigmoidf_(2.0f*sim) + 1e-8f);
                        if (lane < 8) smsum += sj;
                    } else {
                        asln += (double)logf(sigmoidf_(-2.0f*sim) + 1e-8f);
                    }
                }
                #pragma unroll
                for (int m = 32; m; m >>= 1) smsum += __shfl_xor(smsum, m, 64);
                if (lane == 0) {
                    float dd = si - smsum*0.125f;
                    asmo += (double)(dd*dd);
                }
            }
        }
        __syncthreads();
        if (t == 0) curtask_s = nexttask_s;
        __syncthreads();
    }
    __syncthreads();

    // ---- rare block-cooperative ladder fallback (per-entry cell geometry) ----
    int nf = min((int)flnB, 64);
    u32* ovbuf = &wavebuf[0][0][0];    // 2048 u32
    for (int f = 0; f < nf; ++f) {
        u32 ent = flistB[f];
        int fqg = (int)(ent & 0xFFFFu);
        int fcell = (int)(ent >> 16);
        int scene = fcell / NCELL;
        int cid = fcell - scene*NCELL;
        int sbase = scene * M_PTS;
        int lo[3], hi[3]; float lof[3], hif[3]; bool lw[3], hw[3];
        cell_geom(cid, lo, hi, lof, hif, lw, hw);
        int nx = hi[0]-lo[0]+1, ny = hi[1]-lo[1]+1, nz = hi[2]-lo[2]+1;
        int nruns = ny*nz;
        if (t < nruns) {
            int yy = t % ny, zz = t / ny;
            int bc = scene*NCELL + ((lo[2]+zz)*G + (lo[1]+yy))*G + lo[0];
            frunsb[t] = (int)cellstart[bc];
            frunse[t] = (int)cellstart[bc + nx];
        }
        float4 fqc = P4s[fqg];
        float fsq = fmaf(fqc.x, fqc.x, fmaf(fqc.y, fqc.y, fqc.z*fqc.z));
        float fcov = 1e9f;
        float fqd[3] = {fqc.x, fqc.y, fqc.z};
        #pragma unroll
        for (int d = 0; d < 3; ++d) {
            if (!lw[d]) fcov = fminf(fcov, fqd[d] - lof[d]);
            if (!hw[d]) fcov = fminf(fcov, hif[d] - fqd[d]);
        }
        float fg2 = fcov*fcov;
        if (t < 6) cnt6[t] = 0;
        if (t == 0) { ovcnt = 0; smacc = 0.f; }
        __syncthreads();
        u32 c0=0,c1=0,c2=0,c3=0,c4=0,c5=0;
        for (int rr = 0; rr < nruns; ++rr) {
            for (int v = frunsb[rr] + t; v < frunse[rr]; v += 256) {
                float4 pp = P4s[v];
                float sq = fmaf(pp.x, pp.x, fmaf(pp.y, pp.y, pp.z*pp.z));
                float dot = fmaf(fqc.x, pp.x, fmaf(fqc.y, pp.y, fqc.z*pp.z));
                float e2 = fmaf(-2.0f, dot, sq);
                c0 += (e2 < TL0-fsq); c1 += (e2 < TL1-fsq); c2 += (e2 < TL2-fsq);
                c3 += (e2 < TL3-fsq); c4 += (e2 < TL4-fsq); c5 += (e2 < TL5-fsq);
            }
        }
        #pragma unroll
        for (int m = 32; m; m >>= 1) {
            c0 += __shfl_xor(c0, m, 64); c1 += __shfl_xor(c1, m, 64);
            c2 += __shfl_xor(c2, m, 64); c3 += __shfl_xor(c3, m, 64);
            c4 += __shfl_xor(c4, m, 64); c5 += __shfl_xor(c5, m, 64);
        }
        if ((t & 63) == 0) {
            atomicAdd(&cnt6[0], c0); atomicAdd(&cnt6[1], c1);
            atomicAdd(&cnt6[2], c2); atomicAdd(&cnt6[3], c3);
            atomicAdd(&cnt6[4], c4); atomicAdd(&cnt6[5], c5);
        }
        __syncthreads();
        float tau = TL2;
        if (TL3 <= fg2) tau = TL3;
        if (TL4 <= fg2) tau = TL4;
        if (TL5 <= fg2) tau = TL5;
        if      (cnt6[0] >= 32u) tau = TL0;
        else if (cnt6[1] >= 32u) tau = TL1;
        else if (cnt6[2] >= 32u) tau = TL2;
        else if (TL3 <= fg2 && cnt6[3] >= 32u) tau = TL3;
        else if (TL4 <= fg2 && cnt6[4] >= 32u) tau = TL4;
        else if (TL5 <= fg2 && cnt6[5] >= 32u) tau = TL5;
        float ftp = tau - fsq;
        for (int rr = 0; rr < nruns; ++rr) {
            for (int v = frunsb[rr] + t; v < frunse[rr]; v += 256) {
                float4 pp = P4s[v];
                float sq = fmaf(pp.x, pp.x, fmaf(pp.y, pp.y, pp.z*pp.z));
                float dot = fmaf(fqc.x, pp.x, fmaf(fqc.y, pp.y, fqc.z*pp.z));
                float e2 = fmaf(-2.0f, dot, sq);
                if (e2 < ftp) {
                    float d2 = fmaxf(e2 + fsq, 0.0f);
                    u32 key = (__float_as_uint(d2) & KEYMASK) | __float_as_uint(pp.w);
                    u32 pos = atomicAdd(&ovcnt, 1u);
                    if (pos < 2048u) ovbuf[pos] = key;
                }
            }
        }
        __syncthreads();
        u32 Mf = min(ovcnt, 2048u);
        float fsi = S[sbase + (int)__float_as_uint(fqc.w)];
        for (int i = t; i < (int)Mf; i += 256) {
            u32 mykey = ovbuf[i];
            u32 rank = 0;
            for (u32 jj = 0; jj < Mf; ++jj) rank += (ovbuf[jj] < mykey);
            if (rank < 32u) {
                float d2 = __uint_as_float(mykey & KEYMASK);
                u32 jo = mykey & IDXMASK;
                float sj = S[sbase + (int)jo];
                float sd = fabsf(fsi - sj);
                float sim = 1.0f - sd;
                if (rank < 16u) {
                    float d = sqrtf(fmaxf(d2, 1e-24f));
                    float wgt = expf(-10.0f*d);
                    anum += (double)(wgt*sd*sd);
                    aden += (double)wgt;
                    aslp += (double)logf(sigmoidf_(2.0f*sim) + 1e-8f);
                    if (rank < 8u) atomicAdd(&smacc, sj);
                } else {
                    asln += (double)logf(sigmoidf_(-2.0f*sim) + 1e-8f);
                }
            }
        }
        __syncthreads();
        if (t == 0) {
            float dd = fsi - smacc*0.125f;
            asmo += (double)(dd*dd);
        }
        __syncthreads();
    }

    // ---- block reduce + global accumulate + fused final ----
    double v[5] = {anum, aden, aslp, asln, asmo};
    #pragma unroll
    for (int k = 0; k < 5; ++k) {
        for (int m = 32; m; m >>= 1) v[k] += __shfl_xor(v[k], m, 64);
    }
    if (lane == 0) {
        #pragma unroll
        for (int k = 0; k < 5; ++k) lred[w][k] = v[k];
    }
    __syncthreads();
    if (t == 0) {
        #pragma unroll
        for (int k = 0; k < 5; ++k)
            atomicAdd(&accum[k], lred[0][k] + lred[1][k] + lred[2][k] + lred[3][k]);
        __threadfence();
        u32 old = atomicAdd(donecnt, 1u);
        if (old == (u32)(NBLKD - 1)) {
            double a0 = atomicAdd(&accum[0], 0.0);
            double a1 = atomicAdd(&accum[1], 0.0);
            double a2 = atomicAdd(&accum[2], 0.0);
            double a3 = atomicAdd(&accum[3], 0.0);
            double a4 = atomicAdd(&accum[4], 0.0);
            double loss_loc = a0 / fmax(a1, 1e-8);
            double inv = 1.0 / ((double)N_PTS * 16.0);
            double loss_con = -(a2 * inv) - (a3 * inv);
            double loss_sm = a4 / (double)N_PTS;
            out[0] = (float)(loss_loc + 0.5*loss_con + 0.2*loss_sm);
        }
    }
}

extern "C" void kernel_launch(void* const* d_in, const int* in_sizes, int n_in,
                              void* d_out, int out_size, void* d_ws, size_t ws_size,
                              hipStream_t stream) {
    const float* feat   = (const float*)d_in[0];
    const float* coords = (const float*)d_in[1];
    const float* W1 = (const float*)d_in[2];
    const float* b1 = (const float*)d_in[3];
    const float* g1 = (const float*)d_in[4];
    const float* be1= (const float*)d_in[5];
    const float* W2 = (const float*)d_in[6];
    const float* b2 = (const float*)d_in[7];
    const float* g2 = (const float*)d_in[8];
    const float* be2= (const float*)d_in[9];
    const float* W3 = (const float*)d_in[10];
    const float* b3 = (const float*)d_in[11];
    char* ws = (char*)d_ws;

    float* stats1   = (float*)(ws);
    float* stats2   = (float*)(ws + 512);
    u32* gcount     = (u32*)(ws + 1024);
    double* accum   = (double*)(ws + 4480);
    u32* donecnt    = (u32*)(ws + 4520);
    u32* taskctr    = (u32*)(ws + 4524);
    u32* cellstart  = (u32*)(ws + 4544);
    u32* cellptr    = (u32*)(ws + 8008);
    float* S        = (float*)(ws + 11472);
    float4* P4s     = (float4*)(ws + 142544);
    u16* pcell      = (u16*)(ws + 666832);

    hipMemsetAsync(d_ws, 0, 4544, stream);

    hipLaunchKernelGGL(kA, dim3(NBLK), dim3(256), 0, stream,
                       feat, coords, W1, b1, gcount, pcell, stats1);
    hipLaunchKernelGGL(kB, dim3(NBLK), dim3(256), 0, stream,
                       feat, W1, b1, stats1, g1, be1, W2, b2,
                       gcount, cellstart, cellptr, stats2);
    hipLaunchKernelGGL(kC, dim3(NBLK), dim3(256), 0, stream,
                       feat, coords, W1, b1, stats1, g1, be1, W2, b2,
                       stats2, g2, be2, W3, b3, pcell, cellptr, P4s, S);
    hipLaunchKernelGGL(kD, dim3(NBLKD), dim3(256), 0, stream,
                       P4s, cellstart, S, accum, donecnt, taskctr, (float*)d_out);
}